// Round 1
// baseline (287.100 us; speedup 1.0000x reference)
//
#include <hip/hip_runtime.h>
#include <cstdint>

#define QSCALE 0.40824829046386301636f  // 6^-0.5

// ---------------------------------------------------------------------------
// QKV projection for layer 0.  thread = (pixel, jgroup of 18 outputs)
// q written pre-scaled; k/v written interleaved per head: [px][head*12 + {k0..5,v0..5}]
// ---------------------------------------------------------------------------
__global__ __launch_bounds__(256) void qkv_first(
    const float* __restrict__ x, const float* __restrict__ w,
    const float* __restrict__ b, float* __restrict__ qo,
    float* __restrict__ kvo, int npx)
{
  __shared__ float ws_[24 * 72];
  __shared__ float bs[72];
  for (int i = threadIdx.x; i < 24 * 72; i += 256) ws_[i] = w[i];
  if (threadIdx.x < 72) bs[threadIdx.x] = b[threadIdx.x];
  __syncthreads();
  int t = blockIdx.x * 256 + threadIdx.x;
  int p = t >> 2, jg = t & 3;
  if (p >= npx) return;
  float xr[24];
  const float4* xp = (const float4*)(x + (size_t)p * 24);
#pragma unroll
  for (int i = 0; i < 6; ++i) {
    float4 f = xp[i];
    xr[4 * i] = f.x; xr[4 * i + 1] = f.y; xr[4 * i + 2] = f.z; xr[4 * i + 3] = f.w;
  }
#pragma unroll
  for (int jj = 0; jj < 18; ++jj) {
    int j = jg * 18 + jj;
    float acc = bs[j];
#pragma unroll
    for (int c = 0; c < 24; ++c) acc += xr[c] * ws_[c * 72 + j];
    int hd6 = (j % 24) / 6, d = j % 6;
    if (j < 24)      qo[(size_t)p * 24 + j] = acc * QSCALE;
    else if (j < 48) kvo[(size_t)p * 48 + hd6 * 12 + d] = acc;
    else             kvo[(size_t)p * 48 + hd6 * 12 + 6 + d] = acc;
  }
}

// ---------------------------------------------------------------------------
// win=5 layer (layers 0,1).  8x8 query tile, 256 thr = 64 q x 4 heads.
// Fuses: attention -> out-proj -> +residual -> W-maxpool -> next-layer QKV.
// K/V staged transposed in LDS: skv[e][px], px stride 145 (odd -> no bank conflicts)
// ---------------------------------------------------------------------------
__global__ __launch_bounds__(256) void attn_small(
    const float* __restrict__ qb, const float* __restrict__ kvb,
    const float* __restrict__ xres,
    const float* __restrict__ wo, const float* __restrict__ bo,
    const float* __restrict__ wqn, const float* __restrict__ bqn,
    float* __restrict__ xn, float* __restrict__ qn, float* __restrict__ kvn,
    int H, int W)
{
  __shared__ float skv[48 * 145];   // transposed K/V region (<=12x12 px)
  __shared__ float satt[64 * 24];
  __shared__ float swo[576];
  __shared__ float sbo[24];
  __shared__ float swqn[1728];
  __shared__ float sbqn[72];

  const int tid = threadIdx.x;
  const int h0 = blockIdx.y * 8, w0 = blockIdx.x * 8;

  for (int i = tid; i < 576; i += 256) swo[i] = wo[i];
  for (int i = tid; i < 1728; i += 256) swqn[i] = wqn[i];
  if (tid < 24) sbo[tid] = bo[tid];
  if (tid < 72) sbqn[tid] = bqn[tid];

  const int rlo = min(max(h0 - 2, 0), H - 5);
  const int rhi = min(max(h0 + 5, 0), H - 5) + 4;
  const int clo = min(max(w0 - 2, 0), W - 5);
  const int chi = min(max(w0 + 5, 0), W - 5) + 4;
  const int nr = rhi - rlo + 1, nc = chi - clo + 1;  // <= 12

  for (int r = 0; r < nr; ++r) {
    const float* src = kvb + ((size_t)(rlo + r) * W + clo) * 48;
    for (int i = tid; i < nc * 48; i += 256) {
      int c = i / 48, e = i - c * 48;
      skv[e * 145 + r * 12 + c] = src[i];
    }
  }
  __syncthreads();

  // ---- attention: thread = (query, head), exact softmax over 25 keys ----
  const int ql = tid >> 2, head = tid & 3;
  const int qh = h0 + (ql >> 3), qw = w0 + (ql & 7);
  const float* qp = qb + ((size_t)qh * W + qw) * 24 + head * 6;
  const float q0 = qp[0], q1 = qp[1], q2 = qp[2], q3 = qp[3], q4 = qp[4], q5 = qp[5];
  const int sh_ = min(max(qh - 2, 0), H - 5) - rlo;
  const int sw_ = min(max(qw - 2, 0), W - 5) - clo;
  const int kb = head * 12;

  float sc[25];
#pragma unroll
  for (int i = 0; i < 5; ++i) {
#pragma unroll
    for (int j = 0; j < 5; ++j) {
      const float* p = skv + (sh_ + i) * 12 + (sw_ + j);
      sc[i * 5 + j] = q0 * p[(kb + 0) * 145] + q1 * p[(kb + 1) * 145]
                    + q2 * p[(kb + 2) * 145] + q3 * p[(kb + 3) * 145]
                    + q4 * p[(kb + 4) * 145] + q5 * p[(kb + 5) * 145];
    }
  }
  float m = sc[0];
#pragma unroll
  for (int t2 = 1; t2 < 25; ++t2) m = fmaxf(m, sc[t2]);
  float l = 0.f, o0 = 0, o1 = 0, o2 = 0, o3 = 0, o4 = 0, o5 = 0;
#pragma unroll
  for (int i = 0; i < 5; ++i) {
#pragma unroll
    for (int j = 0; j < 5; ++j) {
      const float* p = skv + (sh_ + i) * 12 + (sw_ + j);
      float e = __expf(sc[i * 5 + j] - m);
      l += e;
      o0 += e * p[(kb + 6) * 145];  o1 += e * p[(kb + 7) * 145];
      o2 += e * p[(kb + 8) * 145];  o3 += e * p[(kb + 9) * 145];
      o4 += e * p[(kb + 10) * 145]; o5 += e * p[(kb + 11) * 145];
    }
  }
  {
    const float inv = 1.0f / l;
    float* ao = satt + ql * 24 + head * 6;
    ao[0] = o0 * inv; ao[1] = o1 * inv; ao[2] = o2 * inv;
    ao[3] = o3 * inv; ao[4] = o4 * inv; ao[5] = o5 * inv;
  }
  __syncthreads();

  // ---- out-proj + residual -> ylds (alias skv; skv is dead now) ----
  float* ylds = skv;  // 64*24 floats
  if (tid < 240) {
    const int c = tid % 24, pxg = tid / 24;  // 10 groups
    float wcol[24];
#pragma unroll
    for (int j = 0; j < 24; ++j) wcol[j] = swo[j * 24 + c];
    const float bc = sbo[c];
    for (int px = pxg; px < 64; px += 10) {
      const float* ar = satt + px * 24;
      float a = bc;
#pragma unroll
      for (int j = 0; j < 24; ++j) a += ar[j] * wcol[j];
      const int gh = h0 + (px >> 3), gw = w0 + (px & 7);
      a += xres[((size_t)gh * W + gw) * 24 + c];
      ylds[px * 24 + c] = a;
    }
  }
  __syncthreads();

  // ---- maxpool along W (pairs) -> x_next (global) + xnl (LDS) ----
  float* xnl = skv + 2048;  // 32*24 floats, disjoint from ylds[0..1536)
  const int Wn = W >> 1;
  for (int i = tid; i < 32 * 24; i += 256) {
    const int pp = i / 24, c2 = i - pp * 24;
    const int r = pp >> 2, pc = pp & 3;
    const float v = fmaxf(ylds[(r * 8 + 2 * pc) * 24 + c2],
                          ylds[(r * 8 + 2 * pc + 1) * 24 + c2]);
    xnl[pp * 24 + c2] = v;
    const int gh = h0 + r, gw = (w0 >> 1) + pc;
    xn[((size_t)gh * Wn + gw) * 24 + c2] = v;
  }
  __syncthreads();

  // ---- next-layer QKV on pooled pixels ----
  if (tid < 216) {
    const int j = tid % 72, pg = tid / 72;  // 3 groups
    float wcol[24];
#pragma unroll
    for (int cc = 0; cc < 24; ++cc) wcol[cc] = swqn[cc * 72 + j];
    const float bj = sbqn[j];
    const int hh = (j % 24) / 6, dd = j % 6;
    for (int pp = pg; pp < 32; pp += 3) {
      const float* xr2 = xnl + pp * 24;
      float a = bj;
#pragma unroll
      for (int cc = 0; cc < 24; ++cc) a += xr2[cc] * wcol[cc];
      const int gh = h0 + (pp >> 2), gw = (w0 >> 1) + (pp & 3);
      const size_t gp = (size_t)gh * Wn + gw;
      if (j < 24)      qn[gp * 24 + j] = a * QSCALE;
      else if (j < 48) kvn[gp * 48 + hh * 12 + dd] = a;
      else             kvn[gp * 48 + hh * 12 + 6 + dd] = a;
    }
  }
}

// ---------------------------------------------------------------------------
// win=25 layer (layers 2,3).  H=64, W=88.  4x4 query tile.
// 128 thr = 4 qw x 4 heads x 8 col-slices; each thread owns 4 query rows (R=4
// register reuse of every K/V read).  Chunked (4 key rows) double-buffered LDS
// staging, online softmax with deferred-max (rescale only when s > m+8), final
// 8-slice merge.  LAST: writes transposed output instead of next-layer state.
// ---------------------------------------------------------------------------
template <bool LAST>
__global__ __launch_bounds__(128) void attn_big(
    const float* __restrict__ qb, const float* __restrict__ kvb,
    const float* __restrict__ xres,
    const float* __restrict__ wo, const float* __restrict__ bo,
    const float* __restrict__ wqn, const float* __restrict__ bqn,
    float* __restrict__ xn, float* __restrict__ qn, float* __restrict__ kvn,
    float* __restrict__ dout)
{
  constexpr int H = 64, W = 88;
  __shared__ float skv[2][48 * 113];  // transposed chunk: [e][rr*28+c], stride 113
  __shared__ float satt[16 * 24];
  __shared__ float spart[64 * 64];    // [qid*4+head][cs*8 + {m,l,acc0..5}]
  __shared__ float swo[576];
  __shared__ float sbo[24];
  __shared__ float swqn[1728];
  __shared__ float sbqn[72];

  const int tid = threadIdx.x;  // 128
  const int h0 = blockIdx.y * 4, w0 = blockIdx.x * 4;
  const int tw = tid & 3, head = (tid >> 2) & 3, cs = tid >> 4;  // cs 0..7

  for (int i = tid; i < 576; i += 128) swo[i] = wo[i];
  if (tid < 24) sbo[tid] = bo[tid];
  if (!LAST) {
    for (int i = tid; i < 1728; i += 128) swqn[i] = wqn[i];
    if (tid < 72) sbqn[tid] = bqn[tid];
  }

  const int rlo = min(max(h0 - 12, 0), H - 25);
  const int rhi = min(max(h0 - 9, 0), H - 25) + 24;
  const int clo = min(max(w0 - 12, 0), W - 25);
  const int chi = min(max(w0 - 9, 0), W - 25) + 24;
  const int nr = rhi - rlo + 1, nc = chi - clo + 1;  // 25..28

  const int qw = w0 + tw;
  const int cw0 = min(max(qw - 12, 0), W - 25);  // this query's col-window start
  int ccol[4]; bool cval[4];
#pragma unroll
  for (int i = 0; i < 4; ++i) {
    int c = cs + 8 * i;
    int g = clo + c;
    cval[i] = (c < nc) && (g >= cw0) && (g <= cw0 + 24);
    ccol[i] = min(c, nc - 1);
  }

  float qv[4][6];
  int shq[4];  // block-uniform row-window starts
#pragma unroll
  for (int qi = 0; qi < 4; ++qi) {
    const float* qp = qb + ((size_t)(h0 + qi) * W + qw) * 24 + head * 6;
#pragma unroll
    for (int d = 0; d < 6; ++d) qv[qi][d] = qp[d];
    shq[qi] = min(max(h0 + qi - 12, 0), H - 25);
  }

  float m_[4], l_[4], acc[4][6];
#pragma unroll
  for (int qi = 0; qi < 4; ++qi) {
    m_[qi] = -1e30f; l_[qi] = 0.f;
#pragma unroll
    for (int d = 0; d < 6; ++d) acc[qi][d] = 0.f;
  }

  const int nch = (nr + 3) >> 2;

  auto stage = [&](int ch) {
    float* dst = &skv[ch & 1][0];
    const int rb = rlo + ch * 4;
    const int rc = min(4, nr - ch * 4);
    for (int r = 0; r < rc; ++r) {
      const float* src = kvb + ((size_t)(rb + r) * W + clo) * 48;
      const int rb28 = r * 28;
      for (int i = tid; i < nc * 48; i += 128) {
        int c = i / 48, e = i - c * 48;
        dst[e * 113 + rb28 + c] = src[i];
      }
    }
  };

  stage(0);
  __syncthreads();

  for (int ch = 0; ch < nch; ++ch) {
    if (ch + 1 < nch) stage(ch + 1);
    const float* buf = &skv[ch & 1][0];
    const int rb = rlo + ch * 4;
    const int rc = min(4, nr - ch * 4);
    const int hb = head * 12;
    for (int rr = 0; rr < rc; ++rr) {
      const int rg = rb + rr;
      const int pxr = rr * 28;
#pragma unroll
      for (int i = 0; i < 4; ++i) {
        if (!cval[i]) continue;
        const float* p = buf + pxr + ccol[i];
        const float k0 = p[(hb + 0) * 113], k1 = p[(hb + 1) * 113],
                    k2 = p[(hb + 2) * 113], k3 = p[(hb + 3) * 113],
                    k4 = p[(hb + 4) * 113], k5 = p[(hb + 5) * 113];
        const float v0 = p[(hb + 6) * 113], v1 = p[(hb + 7) * 113],
                    v2 = p[(hb + 8) * 113], v3 = p[(hb + 9) * 113],
                    v4 = p[(hb + 10) * 113], v5 = p[(hb + 11) * 113];
#pragma unroll
        for (int qi = 0; qi < 4; ++qi) {
          if (rg >= shq[qi] && rg <= shq[qi] + 24) {  // block-uniform branch
            float s = qv[qi][0] * k0 + qv[qi][1] * k1 + qv[qi][2] * k2
                    + qv[qi][3] * k3 + qv[qi][4] * k4 + qv[qi][5] * k5;
            float d = s - m_[qi];
            if (d > 8.0f) {  // rare rescale (deferred max)
              float r = __expf(-d);
              l_[qi] *= r;
              acc[qi][0] *= r; acc[qi][1] *= r; acc[qi][2] *= r;
              acc[qi][3] *= r; acc[qi][4] *= r; acc[qi][5] *= r;
              m_[qi] = s; d = 0.f;
            }
            float e = __expf(d);
            l_[qi] += e;
            acc[qi][0] += e * v0; acc[qi][1] += e * v1; acc[qi][2] += e * v2;
            acc[qi][3] += e * v3; acc[qi][4] += e * v4; acc[qi][5] += e * v5;
          }
        }
      }
    }
    __syncthreads();
  }

  // ---- write per-slice partials, merge 8 slices per (query, head) ----
#pragma unroll
  for (int qi = 0; qi < 4; ++qi) {
    float* pp = spart + ((qi * 4 + tw) * 4 + head) * 64 + cs * 8;
    pp[0] = m_[qi]; pp[1] = l_[qi];
#pragma unroll
    for (int d = 0; d < 6; ++d) pp[2 + d] = acc[qi][d];
  }
  __syncthreads();

  if (tid < 64) {
    const float* base = spart + tid * 64;
    float mm = base[0];
#pragma unroll
    for (int s2 = 1; s2 < 8; ++s2) mm = fmaxf(mm, base[s2 * 8]);
    float L = 0.f, A0 = 0, A1 = 0, A2 = 0, A3 = 0, A4 = 0, A5 = 0;
#pragma unroll
    for (int s2 = 0; s2 < 8; ++s2) {
      const float* p = base + s2 * 8;
      float f = __expf(p[0] - mm);
      L += p[1] * f;
      A0 += p[2] * f; A1 += p[3] * f; A2 += p[4] * f;
      A3 += p[5] * f; A4 += p[6] * f; A5 += p[7] * f;
    }
    const float inv = 1.0f / L;
    float* ao = satt + (tid >> 2) * 24 + (tid & 3) * 6;
    ao[0] = A0 * inv; ao[1] = A1 * inv; ao[2] = A2 * inv;
    ao[3] = A3 * inv; ao[4] = A4 * inv; ao[5] = A5 * inv;
  }
  __syncthreads();

  // ---- out-proj + residual; LAST writes transposed output ----
  float* xnl = spart;  // reuse (merge done)
  if (tid < 120) {
    const int c = tid % 24, pxg = tid / 24;  // 5 groups
    float wcol[24];
#pragma unroll
    for (int j = 0; j < 24; ++j) wcol[j] = swo[j * 24 + c];
    const float bc = sbo[c];
    for (int px = pxg; px < 16; px += 5) {
      const float* ar = satt + px * 24;
      float a = bc;
#pragma unroll
      for (int j = 0; j < 24; ++j) a += ar[j] * wcol[j];
      const int gh = h0 + (px >> 2), gw = w0 + (px & 3);
      a += xres[((size_t)gh * W + gw) * 24 + c];
      if (LAST) {
        dout[((size_t)gh * 24 + c) * 88 + gw] = a;  // [H][C][W]
      } else {
        xn[((size_t)gh * W + gw) * 24 + c] = a;
        xnl[px * 24 + c] = a;
      }
    }
  }
  if (!LAST) {
    __syncthreads();
    if (tid < 72) {
      const int j = tid;
      float wcol[24];
#pragma unroll
      for (int cc = 0; cc < 24; ++cc) wcol[cc] = swqn[cc * 72 + j];
      const float bj = sbqn[j];
      const int hh = (j % 24) / 6, dd = j % 6;
      for (int px = 0; px < 16; ++px) {
        const float* xr2 = xnl + px * 24;
        float a = bj;
#pragma unroll
        for (int cc = 0; cc < 24; ++cc) a += xr2[cc] * wcol[cc];
        const int gh = h0 + (px >> 2), gw = w0 + (px & 3);
        const size_t gp = (size_t)gh * W + gw;
        if (j < 24)      qn[gp * 24 + j] = a * QSCALE;
        else if (j < 48) kvn[gp * 48 + hh * 12 + dd] = a;
        else             kvn[gp * 48 + hh * 12 + 6 + dd] = a;
      }
    }
  }
}

// ---------------------------------------------------------------------------
extern "C" void kernel_launch(void* const* d_in, const int* in_sizes, int n_in,
                              void* d_out, int out_size, void* d_ws, size_t ws_size,
                              hipStream_t stream)
{
  const float* x      = (const float*)d_in[0];  // [1][64][352][24]
  const float* qkv_w  = (const float*)d_in[1];  // [4][24][72]
  const float* qkv_b  = (const float*)d_in[2];  // [4][72]
  const float* out_w  = (const float*)d_in[3];  // [4][24][24]
  const float* out_b  = (const float*)d_in[4];  // [4][24]
  float* out = (float*)d_out;                   // [1][64][24][88]
  float* ws = (float*)d_ws;

  const int N0 = 64 * 352, N1 = 64 * 176, N2 = 64 * 88;
  float* q0  = ws;               float* kv0 = q0 + (size_t)N0 * 24;
  float* x1  = kv0 + (size_t)N0 * 48;
  float* q1  = x1 + (size_t)N1 * 24;  float* kv1 = q1 + (size_t)N1 * 24;
  float* x2  = kv1 + (size_t)N1 * 48;
  float* q2  = x2 + (size_t)N2 * 24;  float* kv2 = q2 + (size_t)N2 * 24;
  float* x3  = kv2 + (size_t)N2 * 48;
  float* q3  = x3 + (size_t)N2 * 24;  float* kv3 = q3 + (size_t)N2 * 24;
  // total ~15.2 MB of workspace

  qkv_first<<<(N0 * 4) / 256, 256, 0, stream>>>(x, qkv_w, qkv_b, q0, kv0, N0);

  attn_small<<<dim3(44, 8), 256, 0, stream>>>(
      q0, kv0, x, out_w, out_b, qkv_w + 1728, qkv_b + 72,
      x1, q1, kv1, 64, 352);

  attn_small<<<dim3(22, 8), 256, 0, stream>>>(
      q1, kv1, x1, out_w + 576, out_b + 24, qkv_w + 2 * 1728, qkv_b + 2 * 72,
      x2, q2, kv2, 64, 176);

  attn_big<false><<<dim3(22, 16), 128, 0, stream>>>(
      q2, kv2, x2, out_w + 2 * 576, out_b + 2 * 24, qkv_w + 3 * 1728, qkv_b + 3 * 72,
      x3, q3, kv3, nullptr);

  attn_big<true><<<dim3(22, 16), 128, 0, stream>>>(
      q3, kv3, x3, out_w + 3 * 576, out_b + 3 * 24, nullptr, nullptr,
      nullptr, nullptr, nullptr, out);
}

// Round 3
// 212.075 us; speedup vs baseline: 1.3538x; 1.3538x over previous
//
#include <hip/hip_runtime.h>
#include <cstdint>

#define QSCALE 0.40824829046386301636f  // 6^-0.5

// ---------------------------------------------------------------------------
// QKV projection for layer 0.  thread = (pixel, jgroup of 18 outputs)
// q written pre-scaled; k/v interleaved per head: [px][head*12 + {k0..5,v0..5}]
// ---------------------------------------------------------------------------
__global__ __launch_bounds__(256) void qkv_first(
    const float* __restrict__ x, const float* __restrict__ w,
    const float* __restrict__ b, float* __restrict__ qo,
    float* __restrict__ kvo, int npx)
{
  __shared__ float ws_[24 * 72];
  __shared__ float bs[72];
  for (int i = threadIdx.x; i < 24 * 72; i += 256) ws_[i] = w[i];
  if (threadIdx.x < 72) bs[threadIdx.x] = b[threadIdx.x];
  __syncthreads();
  int t = blockIdx.x * 256 + threadIdx.x;
  int p = t >> 2, jg = t & 3;
  if (p >= npx) return;
  float xr[24];
  const float4* xp = (const float4*)(x + (size_t)p * 24);
#pragma unroll
  for (int i = 0; i < 6; ++i) {
    float4 f = xp[i];
    xr[4 * i] = f.x; xr[4 * i + 1] = f.y; xr[4 * i + 2] = f.z; xr[4 * i + 3] = f.w;
  }
#pragma unroll
  for (int jj = 0; jj < 18; ++jj) {
    int j = jg * 18 + jj;
    float acc = bs[j];
#pragma unroll
    for (int c = 0; c < 24; ++c) acc += xr[c] * ws_[c * 72 + j];
    int hd6 = (j % 24) / 6, d = j % 6;
    if (j < 24)      qo[(size_t)p * 24 + j] = acc * QSCALE;
    else if (j < 48) kvo[(size_t)p * 48 + hd6 * 12 + d] = acc;
    else             kvo[(size_t)p * 48 + hd6 * 12 + 6 + d] = acc;
  }
}

// ---------------------------------------------------------------------------
// win=5 layer (layers 0,1).  8x8 query tile, 256 thr = 64 q x 4 heads.
// K/V in LDS row-major per pixel: skv[px][52] (pad 48->52 keeps float4 align,
// 20-bank stride -> conflict-free b128 reads).  Single-pass online softmax
// with deferred max.  Fuses out-proj + residual + W-maxpool + next-layer QKV.
// ---------------------------------------------------------------------------
__global__ __launch_bounds__(256) void attn_small(
    const float* __restrict__ qb, const float* __restrict__ kvb,
    const float* __restrict__ xres,
    const float* __restrict__ wo, const float* __restrict__ bo,
    const float* __restrict__ wqn, const float* __restrict__ bqn,
    float* __restrict__ xn, float* __restrict__ qn, float* __restrict__ kvn,
    int H, int W)
{
  __shared__ __align__(16) float skv[144 * 52];   // <=12x12 px, 30KB
  __shared__ float satt[64 * 24];
  __shared__ float swo[576];
  __shared__ float sbo[24];
  __shared__ float swqn[1728];
  __shared__ float sbqn[72];

  const int tid = threadIdx.x;
  const int h0 = blockIdx.y * 8, w0 = blockIdx.x * 8;

  for (int i = tid; i < 576; i += 256) swo[i] = wo[i];
  for (int i = tid; i < 1728; i += 256) swqn[i] = wqn[i];
  if (tid < 24) sbo[tid] = bo[tid];
  if (tid < 72) sbqn[tid] = bqn[tid];

  const int rlo = min(max(h0 - 2, 0), H - 5);
  const int rhi = min(max(h0 + 5, 0), H - 5) + 4;
  const int clo = min(max(w0 - 2, 0), W - 5);
  const int chi = min(max(w0 + 5, 0), W - 5) + 4;
  const int nr = rhi - rlo + 1, nc = chi - clo + 1;  // <= 12

  for (int r = 0; r < nr; ++r) {
    const float* src = kvb + ((size_t)(rlo + r) * W + clo) * 48;
    for (int i = tid; i < nc * 12; i += 256) {
      const int c = i / 12, jj = i - c * 12;
      const float4 v = ((const float4*)(src + c * 48))[jj];
      *(float4*)(&skv[(r * 12 + c) * 52 + jj * 4]) = v;
    }
  }
  __syncthreads();

  // ---- attention: thread = (query, head), single-pass online softmax ----
  const int ql = tid >> 2, head = tid & 3;
  const int qh = h0 + (ql >> 3), qw = w0 + (ql & 7);
  const float* qp = qb + ((size_t)qh * W + qw) * 24 + head * 6;
  const float q0 = qp[0], q1 = qp[1], q2 = qp[2], q3 = qp[3], q4 = qp[4], q5 = qp[5];
  const int sh_ = min(max(qh - 2, 0), H - 5) - rlo;
  const int sw_ = min(max(qw - 2, 0), W - 5) - clo;
  const int hb = head * 12;

  float m = -1e30f, l = 0.f;
  float a0 = 0, a1 = 0, a2 = 0, a3 = 0, a4 = 0, a5 = 0;
#pragma unroll
  for (int i = 0; i < 5; ++i) {
#pragma unroll
    for (int j = 0; j < 5; ++j) {
      const float* p = skv + ((sh_ + i) * 12 + (sw_ + j)) * 52 + hb;
      const float4 A = *(const float4*)p;
      const float4 B = *(const float4*)(p + 4);
      const float4 C = *(const float4*)(p + 8);
      const float s = q0 * A.x + q1 * A.y + q2 * A.z + q3 * A.w + q4 * B.x + q5 * B.y;
      float d = s - m;
      if (d > 8.0f) {  // deferred-max rescale (rare)
        const float r = __expf(-d);
        l *= r; a0 *= r; a1 *= r; a2 *= r; a3 *= r; a4 *= r; a5 *= r;
        m = s; d = 0.f;
      }
      const float e = __expf(d);
      l += e;
      a0 += e * B.z; a1 += e * B.w; a2 += e * C.x;
      a3 += e * C.y; a4 += e * C.z; a5 += e * C.w;
    }
  }
  {
    const float inv = 1.0f / l;
    float* ao = satt + ql * 24 + head * 6;
    ao[0] = a0 * inv; ao[1] = a1 * inv; ao[2] = a2 * inv;
    ao[3] = a3 * inv; ao[4] = a4 * inv; ao[5] = a5 * inv;
  }
  __syncthreads();

  // ---- out-proj + residual -> ylds (alias skv; skv is dead now) ----
  float* ylds = skv;  // 64*24 floats
  if (tid < 240) {
    const int c = tid % 24, pxg = tid / 24;  // 10 groups
    float wcol[24];
#pragma unroll
    for (int j = 0; j < 24; ++j) wcol[j] = swo[j * 24 + c];
    const float bc = sbo[c];
    for (int px = pxg; px < 64; px += 10) {
      const float* ar = satt + px * 24;
      float a = bc;
#pragma unroll
      for (int j = 0; j < 24; ++j) a += ar[j] * wcol[j];
      const int gh = h0 + (px >> 3), gw = w0 + (px & 7);
      a += xres[((size_t)gh * W + gw) * 24 + c];
      ylds[px * 24 + c] = a;
    }
  }
  __syncthreads();

  // ---- maxpool along W (pairs) -> x_next (global) + xnl (LDS) ----
  float* xnl = skv + 2048;  // 32*24 floats, disjoint from ylds[0..1536)
  const int Wn = W >> 1;
  for (int i = tid; i < 32 * 24; i += 256) {
    const int pp = i / 24, c2 = i - pp * 24;
    const int r = pp >> 2, pc = pp & 3;
    const float v = fmaxf(ylds[(r * 8 + 2 * pc) * 24 + c2],
                          ylds[(r * 8 + 2 * pc + 1) * 24 + c2]);
    xnl[pp * 24 + c2] = v;
    const int gh = h0 + r, gw = (w0 >> 1) + pc;
    xn[((size_t)gh * Wn + gw) * 24 + c2] = v;
  }
  __syncthreads();

  // ---- next-layer QKV on pooled pixels ----
  if (tid < 216) {
    const int j = tid % 72, pg = tid / 72;  // 3 groups
    float wcol[24];
#pragma unroll
    for (int cc = 0; cc < 24; ++cc) wcol[cc] = swqn[cc * 72 + j];
    const float bj = sbqn[j];
    const int hh = (j % 24) / 6, dd = j % 6;
    for (int pp = pg; pp < 32; pp += 3) {
      const float* xr2 = xnl + pp * 24;
      float a = bj;
#pragma unroll
      for (int cc = 0; cc < 24; ++cc) a += xr2[cc] * wcol[cc];
      const int gh = h0 + (pp >> 2), gw = (w0 >> 1) + (pp & 3);
      const size_t gp = (size_t)gh * Wn + gw;
      if (j < 24)      qn[gp * 24 + j] = a * QSCALE;
      else if (j < 48) kvn[gp * 48 + hh * 12 + dd] = a;
      else             kvn[gp * 48 + hh * 12 + 6 + dd] = a;
    }
  }
}

// ---------------------------------------------------------------------------
// win=25 layer (layers 2,3).  H=64, W=88.  4x2 query tile, 128 thr =
// qw(2) x head(4) x col-slice(16).  Each thread: 4 query rows in registers,
// <=2 window cols (cs, cs+16).  K/V row-major [px][52] in LDS, 2-row
// double-buffered chunks, 3x ds_read_b128 per key.  Slice merge via
// __shfl_xor butterflies over 16 lanes (no LDS).  LAST: transposed output.
// ---------------------------------------------------------------------------
template <bool LAST>
__global__ __launch_bounds__(128, 2) void attn_big(
    const float* __restrict__ qb, const float* __restrict__ kvb,
    const float* __restrict__ xres,
    const float* __restrict__ wo, const float* __restrict__ bo,
    const float* __restrict__ wqn, const float* __restrict__ bqn,
    float* __restrict__ xn, float* __restrict__ qn, float* __restrict__ kvn,
    float* __restrict__ dout)
{
  constexpr int H = 64, W = 88;
  __shared__ __align__(16) float skv[2][2 * 26 * 52];  // 2-row chunks, 21.6KB
  __shared__ float satt[8 * 24];
  __shared__ float swo[576];
  __shared__ float sbo[24];
  __shared__ float swqn[1728];
  __shared__ float sbqn[72];

  const int tid = threadIdx.x;  // 128
  const int h0 = blockIdx.y * 4, w0 = blockIdx.x * 2;
  const int cs = tid & 15, head = (tid >> 4) & 3, tw = tid >> 6;  // wave = qw

  for (int i = tid; i < 576; i += 128) swo[i] = wo[i];
  if (tid < 24) sbo[tid] = bo[tid];
  if (!LAST) {
    for (int i = tid; i < 1728; i += 128) swqn[i] = wqn[i];
    if (tid < 72) sbqn[tid] = bqn[tid];
  }

  const int rlo = min(max(h0 - 12, 0), H - 25);
  const int rhi = min(max(h0 - 9, 0), H - 25) + 24;
  const int clo = min(max(w0 - 12, 0), W - 25);
  const int chi = min(max(w0 - 11, 0), W - 25) + 24;
  const int nr = rhi - rlo + 1;           // 25..28
  const int nc = chi - clo + 1;           // 25..26

  const int qw = w0 + tw;
  const int cw0 = min(max(qw - 12, 0), W - 25);
  bool cval[2]; int ccol[2];
#pragma unroll
  for (int i = 0; i < 2; ++i) {
    const int c = cs + 16 * i, g = clo + c;
    cval[i] = (c < nc) && (g >= cw0) && (g <= cw0 + 24);
    ccol[i] = c;
  }

  float qv[4][6];
  int shq[4];
#pragma unroll
  for (int qi = 0; qi < 4; ++qi) {
    const float* qp = qb + ((size_t)(h0 + qi) * W + qw) * 24 + head * 6;
#pragma unroll
    for (int d = 0; d < 6; ++d) qv[qi][d] = qp[d];
    shq[qi] = min(max(h0 + qi - 12, 0), H - 25);
  }

  float m_[4], l_[4], acc[4][6];
#pragma unroll
  for (int qi = 0; qi < 4; ++qi) {
    m_[qi] = -1e30f; l_[qi] = 0.f;
#pragma unroll
    for (int d = 0; d < 6; ++d) acc[qi][d] = 0.f;
  }

  const int nch = (nr + 1) >> 1;

  auto stage = [&](int ch) {
    float* dst = &skv[ch & 1][0];
    const int rb = rlo + ch * 2;
    const int rc = min(2, nr - ch * 2);
    for (int r = 0; r < rc; ++r) {
      const float* src = kvb + ((size_t)(rb + r) * W + clo) * 48;
      for (int i = tid; i < 26 * 12; i += 128) {
        const int c = i / 12, jj = i - c * 12;
        const int c_src = min(c, nc - 1);
        const float4 v = ((const float4*)(src + c_src * 48))[jj];
        *(float4*)(&dst[(r * 26 + c) * 52 + jj * 4]) = v;
      }
    }
  };

  stage(0);
  __syncthreads();

  const int hb = head * 12;
  for (int ch = 0; ch < nch; ++ch) {
    if (ch + 1 < nch) stage(ch + 1);
    const float* buf = &skv[ch & 1][0];
    const int rb = rlo + ch * 2;
    const int rc = min(2, nr - ch * 2);
    for (int rr = 0; rr < rc; ++rr) {
      const int rg = rb + rr;
#pragma unroll
      for (int ii = 0; ii < 2; ++ii) {
        if (!cval[ii]) continue;
        const float* p = buf + (rr * 26 + ccol[ii]) * 52 + hb;
        const float4 A = *(const float4*)p;
        const float4 B = *(const float4*)(p + 4);
        const float4 C = *(const float4*)(p + 8);
#pragma unroll
        for (int qi = 0; qi < 4; ++qi) {
          if (rg >= shq[qi] && rg <= shq[qi] + 24) {  // block-uniform branch
            const float s = qv[qi][0] * A.x + qv[qi][1] * A.y + qv[qi][2] * A.z
                          + qv[qi][3] * A.w + qv[qi][4] * B.x + qv[qi][5] * B.y;
            float d = s - m_[qi];
            if (d > 8.0f) {
              const float r = __expf(-d);
              l_[qi] *= r;
              acc[qi][0] *= r; acc[qi][1] *= r; acc[qi][2] *= r;
              acc[qi][3] *= r; acc[qi][4] *= r; acc[qi][5] *= r;
              m_[qi] = s; d = 0.f;
            }
            const float e = __expf(d);
            l_[qi] += e;
            acc[qi][0] += e * B.z; acc[qi][1] += e * B.w; acc[qi][2] += e * C.x;
            acc[qi][3] += e * C.y; acc[qi][4] += e * C.z; acc[qi][5] += e * C.w;
          }
        }
      }
    }
    __syncthreads();
  }

  // ---- merge 16 col-slices per (query,head) via shfl butterflies ----
#pragma unroll
  for (int mask = 1; mask < 16; mask <<= 1) {
#pragma unroll
    for (int qi = 0; qi < 4; ++qi) {
      const float om = __shfl_xor(m_[qi], mask);
      const float ol = __shfl_xor(l_[qi], mask);
      float oa[6];
#pragma unroll
      for (int d = 0; d < 6; ++d) oa[d] = __shfl_xor(acc[qi][d], mask);
      const float nm = fmaxf(m_[qi], om);
      const float f1 = __expf(m_[qi] - nm), f2 = __expf(om - nm);
      l_[qi] = l_[qi] * f1 + ol * f2;
#pragma unroll
      for (int d = 0; d < 6; ++d) acc[qi][d] = acc[qi][d] * f1 + oa[d] * f2;
      m_[qi] = nm;
    }
  }
  if (cs == 0) {
#pragma unroll
    for (int qi = 0; qi < 4; ++qi) {
      const float inv = 1.0f / l_[qi];
      float* ao = satt + (qi * 2 + tw) * 24 + head * 6;
#pragma unroll
      for (int d = 0; d < 6; ++d) ao[d] = acc[qi][d] * inv;
    }
  }
  __syncthreads();

  // ---- out-proj + residual; LAST writes transposed output ----
  float* xnl = &skv[0][0];  // dead, reuse for pooled-x equivalent (8*24)
  for (int i = tid; i < 192; i += 128) {
    const int c = i % 24, px = i / 24;
    const float* ar = satt + px * 24;
    float a = sbo[c];
#pragma unroll
    for (int j = 0; j < 24; ++j) a += ar[j] * swo[j * 24 + c];
    const int gh = h0 + (px >> 1), gw = w0 + (px & 1);
    a += xres[((size_t)gh * W + gw) * 24 + c];
    if (LAST) {
      dout[((size_t)gh * 24 + c) * 88 + gw] = a;  // [H][C][W]
    } else {
      xn[((size_t)gh * W + gw) * 24 + c] = a;
      xnl[px * 24 + c] = a;
    }
  }
  if (!LAST) {
    __syncthreads();
    for (int idx = tid; idx < 576; idx += 128) {
      const int j = idx % 72, px = idx / 72;
      const float* xr2 = xnl + px * 24;
      float a = sbqn[j];
#pragma unroll
      for (int cc = 0; cc < 24; ++cc) a += xr2[cc] * swqn[cc * 72 + j];
      const int hh = (j % 24) / 6, dd = j % 6;
      const int gh = h0 + (px >> 1), gw = w0 + (px & 1);
      const size_t gp = (size_t)gh * W + gw;
      if (j < 24)      qn[gp * 24 + j] = a * QSCALE;
      else if (j < 48) kvn[gp * 48 + hh * 12 + dd] = a;
      else             kvn[gp * 48 + hh * 12 + 6 + dd] = a;
    }
  }
}

// ---------------------------------------------------------------------------
extern "C" void kernel_launch(void* const* d_in, const int* in_sizes, int n_in,
                              void* d_out, int out_size, void* d_ws, size_t ws_size,
                              hipStream_t stream)
{
  const float* x      = (const float*)d_in[0];  // [1][64][352][24]
  const float* qkv_w  = (const float*)d_in[1];  // [4][24][72]
  const float* qkv_b  = (const float*)d_in[2];  // [4][72]
  const float* out_w  = (const float*)d_in[3];  // [4][24][24]
  const float* out_b  = (const float*)d_in[4];  // [4][24]
  float* out = (float*)d_out;                   // [1][64][24][88]
  float* ws = (float*)d_ws;

  const int N0 = 64 * 352, N1 = 64 * 176, N2 = 64 * 88;
  float* q0  = ws;               float* kv0 = q0 + (size_t)N0 * 24;
  float* x1  = kv0 + (size_t)N0 * 48;
  float* q1  = x1 + (size_t)N1 * 24;  float* kv1 = q1 + (size_t)N1 * 24;
  float* x2  = kv1 + (size_t)N1 * 48;
  float* q2  = x2 + (size_t)N2 * 24;  float* kv2 = q2 + (size_t)N2 * 24;
  float* x3  = kv2 + (size_t)N2 * 48;
  float* q3  = x3 + (size_t)N2 * 24;  float* kv3 = q3 + (size_t)N2 * 24;

  qkv_first<<<(N0 * 4) / 256, 256, 0, stream>>>(x, qkv_w, qkv_b, q0, kv0, N0);

  attn_small<<<dim3(44, 8), 256, 0, stream>>>(
      q0, kv0, x, out_w, out_b, qkv_w + 1728, qkv_b + 72,
      x1, q1, kv1, 64, 352);

  attn_small<<<dim3(22, 8), 256, 0, stream>>>(
      q1, kv1, x1, out_w + 576, out_b + 24, qkv_w + 2 * 1728, qkv_b + 2 * 72,
      x2, q2, kv2, 64, 176);

  attn_big<false><<<dim3(44, 16), 128, 0, stream>>>(
      q2, kv2, x2, out_w + 2 * 576, out_b + 2 * 24, qkv_w + 3 * 1728, qkv_b + 3 * 72,
      x3, q3, kv3, nullptr);

  attn_big<true><<<dim3(44, 16), 128, 0, stream>>>(
      q3, kv3, x3, out_w + 3 * 576, out_b + 3 * 24, nullptr, nullptr,
      nullptr, nullptr, nullptr, out);
}

// Round 4
// 165.070 us; speedup vs baseline: 1.7393x; 1.2848x over previous
//
#include <hip/hip_runtime.h>
#include <cstdint>

#define QSCALE 0.40824829046386301636f  // 6^-0.5

// ============================================================================
// qkv_first: x[N][24] -> q[4][N][6] (pre-scaled), kv[4][N][12] ({k6,v6})
// ============================================================================
__global__ __launch_bounds__(256) void qkv_first(
    const float* __restrict__ x, const float* __restrict__ w,
    const float* __restrict__ b, float* __restrict__ q,
    float* __restrict__ kv, int npx)
{
  __shared__ __align__(16) float swT[72 * 24];  // transposed: swT[j][c]
  __shared__ float sb[72];
  for (int i = threadIdx.x; i < 1728; i += 256) swT[(i % 72) * 24 + i / 72] = w[i];
  if (threadIdx.x < 72) sb[threadIdx.x] = b[threadIdx.x];
  __syncthreads();
  const int t = blockIdx.x * 256 + threadIdx.x;
  const int p = t >> 2, jg = t & 3;
  if (p >= npx) return;
  float xr[24];
  const float4* xp = (const float4*)(x + (size_t)p * 24);
#pragma unroll
  for (int i = 0; i < 6; ++i) {
    const float4 f = xp[i];
    xr[4*i] = f.x; xr[4*i+1] = f.y; xr[4*i+2] = f.z; xr[4*i+3] = f.w;
  }
#pragma unroll
  for (int jj = 0; jj < 18; ++jj) {
    const int j = jg * 18 + jj;
    const float* wr = &swT[j * 24];
    float acc = sb[j];
#pragma unroll
    for (int c = 0; c < 24; ++c) acc += xr[c] * wr[c];
    if (j < 24)      q[((size_t)(j / 6) * npx + p) * 6 + j % 6] = acc * QSCALE;
    else if (j < 48) { const int u = j - 24; kv[((size_t)(u / 6) * npx + p) * 12 + u % 6] = acc; }
    else             { const int u = j - 48; kv[((size_t)(u / 6) * npx + p) * 12 + 6 + u % 6] = acc; }
  }
}

// ============================================================================
// attn5: win=5 attention, one head per block.  Block = 8x8 queries, 128 thr =
// (q 64) x (row-slice 2).  Whole per-head window (<=12x12 px x 12 f = 6.9KB)
// staged once -> single barrier -> straight-line compute.  Interleaved row
// slices (rr = sr, sr+2, ...) keep the wave's loop structure uniform.
// Output: att[px][24] (this head's 6 floats).
// ============================================================================
__global__ __launch_bounds__(128) void attn5(
    const float* __restrict__ q, const float* __restrict__ kv,
    float* __restrict__ att, int H, int W)
{
  __shared__ __align__(16) float skv[12 * 12 * 12];
  const int tid = threadIdx.x;
  const int h0 = blockIdx.y * 8, w0 = blockIdx.x * 8, hd = blockIdx.z;
  const int N = H * W;
  const int rlo = min(max(h0 - 2, 0), H - 5);
  const int nr  = min(max(h0 + 5, 0), H - 5) + 4 - rlo + 1;   // <= 12
  const int clo = min(max(w0 - 2, 0), W - 5);
  const int nc  = min(max(w0 + 5, 0), W - 5) + 4 - clo + 1;   // <= 12
  const float* kvh = kv + (size_t)hd * N * 12;
  const int ncc = nc * 3;
  for (int i = tid; i < nr * ncc; i += 128) {
    const int r = i / ncc, c4 = i - r * ncc;
    const float4 v = ((const float4*)(kvh + ((size_t)(rlo + r) * W + clo) * 12))[c4];
    ((float4*)skv)[r * 36 + c4] = v;   // LDS row stride = 12 px * 12 f
  }
  __syncthreads();

  const int ql = tid >> 1, sr = tid & 1;
  const int qh = h0 + (ql >> 3), qw = w0 + (ql & 7);
  const float* qp = q + ((size_t)hd * N + (size_t)qh * W + qw) * 6;
  const float q0 = qp[0], q1 = qp[1], q2 = qp[2], q3 = qp[3], q4 = qp[4], q5 = qp[5];
  const int shq = min(max(qh - 2, 0), H - 5) - rlo;
  const int swq = min(max(qw - 2, 0), W - 5) - clo;

  float m = -1e30f, l = 0.f, a0 = 0, a1 = 0, a2 = 0, a3 = 0, a4 = 0, a5 = 0;
  for (int rr = sr; rr < 5; rr += 2) {       // sr=0: rows 0,2,4; sr=1: 1,3
    const float* rowp = skv + ((shq + rr) * 12 + swq) * 12;
#pragma unroll
    for (int cc = 0; cc < 5; ++cc) {
      const float* p = rowp + cc * 12;
      const float4 A = *(const float4*)p;
      const float4 B = *(const float4*)(p + 4);
      const float4 C = *(const float4*)(p + 8);
      const float s = q0*A.x + q1*A.y + q2*A.z + q3*A.w + q4*B.x + q5*B.y;
      float d = s - m;
      if (d > 8.0f) {                        // deferred-max rescale (rare)
        const float r2 = __expf(-d);
        l *= r2; a0 *= r2; a1 *= r2; a2 *= r2; a3 *= r2; a4 *= r2; a5 *= r2;
        m = s; d = 0.f;
      }
      const float e = __expf(d);
      l += e;
      a0 += e*B.z; a1 += e*B.w; a2 += e*C.x;
      a3 += e*C.y; a4 += e*C.z; a5 += e*C.w;
    }
  }
  {  // merge the sr pair (adjacent lanes)
    const float om = __shfl_xor(m, 1), ol = __shfl_xor(l, 1);
    const float o0 = __shfl_xor(a0, 1), o1 = __shfl_xor(a1, 1), o2 = __shfl_xor(a2, 1);
    const float o3 = __shfl_xor(a3, 1), o4 = __shfl_xor(a4, 1), o5 = __shfl_xor(a5, 1);
    const float nm = fmaxf(m, om);
    const float f1 = __expf(m - nm), f2 = __expf(om - nm);
    l = l*f1 + ol*f2;
    a0 = a0*f1 + o0*f2; a1 = a1*f1 + o1*f2; a2 = a2*f1 + o2*f2;
    a3 = a3*f1 + o3*f2; a4 = a4*f1 + o4*f2; a5 = a5*f1 + o5*f2;
  }
  if (sr == 0) {
    const float inv = 1.0f / l;
    float* ap = att + ((size_t)qh * W + qw) * 24 + hd * 6;
    ((float2*)ap)[0] = make_float2(a0*inv, a1*inv);
    ((float2*)ap)[1] = make_float2(a2*inv, a3*inv);
    ((float2*)ap)[2] = make_float2(a4*inv, a5*inv);
  }
}

// ============================================================================
// attn25: win=25 attention, one head per block.  Block = 4x8 queries, 256 thr
// = (q 32) x (slice 8 = row-par 2 x col-par 4).  Whole per-head window union
// (<=28x32 px x 12 f = 43KB) staged once -> one barrier -> compute.  Each
// thread iterates its OWN query's 25x25 window (no masking waste), interleaved
// rows (stride 2) / cols (stride 4).  shfl_xor butterfly merge over 8 lanes.
// ============================================================================
__global__ __launch_bounds__(256) void attn25(
    const float* __restrict__ q, const float* __restrict__ kv,
    float* __restrict__ att)
{
  constexpr int H = 64, W = 88, N = H * W;
  __shared__ __align__(16) float skv[28 * 32 * 12];   // 43 KB
  const int tid = threadIdx.x;
  const int h0 = blockIdx.y * 4, w0 = blockIdx.x * 8, hd = blockIdx.z;
  const int rlo = min(max(h0 - 12, 0), H - 25);
  const int nr  = min(max(h0 + 3 - 12, 0), H - 25) + 24 - rlo + 1;  // <= 28
  const int clo = min(max(w0 - 12, 0), W - 25);
  const int nc  = min(max(w0 + 7 - 12, 0), W - 25) + 24 - clo + 1;  // <= 32
  const float* kvh = kv + (size_t)hd * N * 12;
  const int ncc = nc * 3;
  for (int i = tid; i < nr * ncc; i += 256) {
    const int r = i / ncc, c4 = i - r * ncc;
    const float4 v = ((const float4*)(kvh + ((size_t)(rlo + r) * W + clo) * 12))[c4];
    ((float4*)skv)[r * 96 + c4] = v;   // LDS row stride = 32 px * 12 f
  }
  __syncthreads();

  const int ql = tid >> 3, s = tid & 7, sr = s >> 2, sc = s & 3;
  const int qh = h0 + (ql >> 3), qw = w0 + (ql & 7);
  const float* qp = q + ((size_t)hd * N + (size_t)qh * W + qw) * 6;
  const float q0 = qp[0], q1 = qp[1], q2 = qp[2], q3 = qp[3], q4 = qp[4], q5 = qp[5];
  const int shq = min(max(qh - 12, 0), H - 25) - rlo;
  const int swq = min(max(qw - 12, 0), W - 25) - clo;

  float m = -1e30f, l = 0.f, a0 = 0, a1 = 0, a2 = 0, a3 = 0, a4 = 0, a5 = 0;
  for (int rr = sr; rr < 25; rr += 2) {       // 13 or 12 rows
    const float* rowp = skv + ((shq + rr) * 32 + swq) * 12;
    for (int cc = sc; cc < 25; cc += 4) {     // 7 or 6 cols
      const float* p = rowp + cc * 12;
      const float4 A = *(const float4*)p;
      const float4 B = *(const float4*)(p + 4);
      const float4 C = *(const float4*)(p + 8);
      const float s2 = q0*A.x + q1*A.y + q2*A.z + q3*A.w + q4*B.x + q5*B.y;
      float d = s2 - m;
      if (d > 8.0f) {
        const float r2 = __expf(-d);
        l *= r2; a0 *= r2; a1 *= r2; a2 *= r2; a3 *= r2; a4 *= r2; a5 *= r2;
        m = s2; d = 0.f;
      }
      const float e = __expf(d);
      l += e;
      a0 += e*B.z; a1 += e*B.w; a2 += e*C.x;
      a3 += e*C.y; a4 += e*C.z; a5 += e*C.w;
    }
  }
  // butterfly merge over the 8 slice lanes
#pragma unroll
  for (int mask = 1; mask <= 4; mask <<= 1) {
    const float om = __shfl_xor(m, mask), ol = __shfl_xor(l, mask);
    const float o0 = __shfl_xor(a0, mask), o1 = __shfl_xor(a1, mask), o2 = __shfl_xor(a2, mask);
    const float o3 = __shfl_xor(a3, mask), o4 = __shfl_xor(a4, mask), o5 = __shfl_xor(a5, mask);
    const float nm = fmaxf(m, om);
    const float f1 = __expf(m - nm), f2 = __expf(om - nm);
    m = nm;
    l = l*f1 + ol*f2;
    a0 = a0*f1 + o0*f2; a1 = a1*f1 + o1*f2; a2 = a2*f1 + o2*f2;
    a3 = a3*f1 + o3*f2; a4 = a4*f1 + o4*f2; a5 = a5*f1 + o5*f2;
  }
  if (s == 0) {
    const float inv = 1.0f / l;
    float* ap = att + ((size_t)qh * W + qw) * 24 + hd * 6;
    ((float2*)ap)[0] = make_float2(a0*inv, a1*inv);
    ((float2*)ap)[1] = make_float2(a2*inv, a3*inv);
    ((float2*)ap)[2] = make_float2(a4*inv, a5*inv);
  }
}

// ============================================================================
// glue_pool: y = att@Wo+bo+res; pool W-pairs; next-layer qkv on pooled px.
// Block = 64 pooled px (128 src px, contiguous since src = 2*pooled linearly).
// Phase1: (src px 128, half 2) -> 12 channels each -> y in LDS.
// Phase2: (pooled px 64, jgroup 4) -> pool + 18 of 72 qkv outputs.
// ============================================================================
__global__ __launch_bounds__(256) void glue_pool(
    const float* __restrict__ att, const float* __restrict__ xres,
    const float* __restrict__ wo, const float* __restrict__ bo,
    const float* __restrict__ wq, const float* __restrict__ bq,
    float* __restrict__ xn, float* __restrict__ qn, float* __restrict__ kvn,
    int Nn)
{
  __shared__ __align__(16) float swoT[24 * 24];
  __shared__ float sbo[24];
  __shared__ __align__(16) float swqT[72 * 24];
  __shared__ float sbq[72];
  __shared__ __align__(16) float sy[128 * 28];
  const int tid = threadIdx.x;
  for (int i = tid; i < 576; i += 256) swoT[(i % 24) * 24 + i / 24] = wo[i];
  for (int i = tid; i < 1728; i += 256) swqT[(i % 72) * 24 + i / 72] = wq[i];
  if (tid < 24) sbo[tid] = bo[tid];
  if (tid < 72) sbq[tid] = bq[tid];
  __syncthreads();

  {  // phase 1
    const int lpx = tid >> 1, half = tid & 1;
    const size_t spx = (size_t)blockIdx.x * 128 + lpx;
    float ar[24];
    const float4* ap = (const float4*)(att + spx * 24);
#pragma unroll
    for (int i = 0; i < 6; ++i) {
      const float4 f = ap[i];
      ar[4*i] = f.x; ar[4*i+1] = f.y; ar[4*i+2] = f.z; ar[4*i+3] = f.w;
    }
    float res[12];
    const float4* rp = (const float4*)(xres + spx * 24 + half * 12);
#pragma unroll
    for (int i = 0; i < 3; ++i) {
      const float4 f = rp[i];
      res[4*i] = f.x; res[4*i+1] = f.y; res[4*i+2] = f.z; res[4*i+3] = f.w;
    }
#pragma unroll
    for (int k = 0; k < 12; ++k) {
      const int c = half * 12 + k;
      const float* wr = &swoT[c * 24];
      float acc = sbo[c] + res[k];
#pragma unroll
      for (int j = 0; j < 24; ++j) acc += ar[j] * wr[j];
      sy[lpx * 28 + c] = acc;
    }
  }
  __syncthreads();
  {  // phase 2
    const int ppl = tid >> 2, jg = tid & 3;
    const size_t gp = (size_t)blockIdx.x * 64 + ppl;
    float xp[24];
    const float* y0 = &sy[(2 * ppl) * 28];
    const float* y1 = &sy[(2 * ppl + 1) * 28];
#pragma unroll
    for (int c = 0; c < 24; ++c) xp[c] = fmaxf(y0[c], y1[c]);
    if (jg == 0) {
      float4* xo = (float4*)(xn + gp * 24);
#pragma unroll
      for (int i = 0; i < 6; ++i)
        xo[i] = make_float4(xp[4*i], xp[4*i+1], xp[4*i+2], xp[4*i+3]);
    }
#pragma unroll
    for (int jj = 0; jj < 18; ++jj) {
      const int j = jg * 18 + jj;
      const float* wr = &swqT[j * 24];
      float acc = sbq[j];
#pragma unroll
      for (int c = 0; c < 24; ++c) acc += xp[c] * wr[c];
      if (j < 24)      qn[((size_t)(j / 6) * Nn + gp) * 6 + j % 6] = acc * QSCALE;
      else if (j < 48) { const int u = j - 24; kvn[((size_t)(u / 6) * Nn + gp) * 12 + u % 6] = acc; }
      else             { const int u = j - 48; kvn[((size_t)(u / 6) * Nn + gp) * 12 + 6 + u % 6] = acc; }
    }
  }
}

// ============================================================================
// glue_nopool: y = att@Wo+bo+res -> xn; next-layer qkv on y (no pooling).
// Block = 64 px.  Phase1: (px, quarter) -> 6 channels.  Phase2: (px, jg) -> 18.
// ============================================================================
__global__ __launch_bounds__(256) void glue_nopool(
    const float* __restrict__ att, const float* __restrict__ xres,
    const float* __restrict__ wo, const float* __restrict__ bo,
    const float* __restrict__ wq, const float* __restrict__ bq,
    float* __restrict__ xn, float* __restrict__ qn, float* __restrict__ kvn,
    int Nn)
{
  __shared__ __align__(16) float swoT[24 * 24];
  __shared__ float sbo[24];
  __shared__ __align__(16) float swqT[72 * 24];
  __shared__ float sbq[72];
  __shared__ __align__(16) float sy[64 * 28];
  const int tid = threadIdx.x;
  for (int i = tid; i < 576; i += 256) swoT[(i % 24) * 24 + i / 24] = wo[i];
  for (int i = tid; i < 1728; i += 256) swqT[(i % 72) * 24 + i / 72] = wq[i];
  if (tid < 24) sbo[tid] = bo[tid];
  if (tid < 72) sbq[tid] = bq[tid];
  __syncthreads();

  {  // phase 1
    const int lpx = tid >> 2, qt = tid & 3;
    const size_t spx = (size_t)blockIdx.x * 64 + lpx;
    float ar[24];
    const float4* ap = (const float4*)(att + spx * 24);
#pragma unroll
    for (int i = 0; i < 6; ++i) {
      const float4 f = ap[i];
      ar[4*i] = f.x; ar[4*i+1] = f.y; ar[4*i+2] = f.z; ar[4*i+3] = f.w;
    }
#pragma unroll
    for (int k = 0; k < 6; ++k) {
      const int c = qt * 6 + k;
      const float* wr = &swoT[c * 24];
      float acc = sbo[c] + xres[spx * 24 + c];
#pragma unroll
      for (int j = 0; j < 24; ++j) acc += ar[j] * wr[j];
      sy[lpx * 28 + c] = acc;
      xn[spx * 24 + c] = acc;
    }
  }
  __syncthreads();
  {  // phase 2
    const int lpx = tid >> 2, jg = tid & 3;
    const size_t gp = (size_t)blockIdx.x * 64 + lpx;
    const float* yr = &sy[lpx * 28];
    float xp[24];
#pragma unroll
    for (int c = 0; c < 24; ++c) xp[c] = yr[c];
#pragma unroll
    for (int jj = 0; jj < 18; ++jj) {
      const int j = jg * 18 + jj;
      const float* wr = &swqT[j * 24];
      float acc = sbq[j];
#pragma unroll
      for (int c = 0; c < 24; ++c) acc += xp[c] * wr[c];
      if (j < 24)      qn[((size_t)(j / 6) * Nn + gp) * 6 + j % 6] = acc * QSCALE;
      else if (j < 48) { const int u = j - 24; kvn[((size_t)(u / 6) * Nn + gp) * 12 + u % 6] = acc; }
      else             { const int u = j - 48; kvn[((size_t)(u / 6) * Nn + gp) * 12 + 6 + u % 6] = acc; }
    }
  }
}

// ============================================================================
// final_out: y = att@Wo+bo+res, stored transposed as dout[H][C][W].
// Block = 128 px x 2 halves.
// ============================================================================
__global__ __launch_bounds__(256) void final_out(
    const float* __restrict__ att, const float* __restrict__ xres,
    const float* __restrict__ wo, const float* __restrict__ bo,
    float* __restrict__ dout)
{
  __shared__ __align__(16) float swoT[24 * 24];
  __shared__ float sbo[24];
  const int tid = threadIdx.x;
  for (int i = tid; i < 576; i += 256) swoT[(i % 24) * 24 + i / 24] = wo[i];
  if (tid < 24) sbo[tid] = bo[tid];
  __syncthreads();
  const int lpx = tid >> 1, half = tid & 1;
  const size_t spx = (size_t)blockIdx.x * 128 + lpx;
  const int gh = (int)(spx / 88), gw = (int)(spx % 88);
  float ar[24];
  const float4* ap = (const float4*)(att + spx * 24);
#pragma unroll
  for (int i = 0; i < 6; ++i) {
    const float4 f = ap[i];
    ar[4*i] = f.x; ar[4*i+1] = f.y; ar[4*i+2] = f.z; ar[4*i+3] = f.w;
  }
  float res[12];
  const float4* rp = (const float4*)(xres + spx * 24 + half * 12);
#pragma unroll
  for (int i = 0; i < 3; ++i) {
    const float4 f = rp[i];
    res[4*i] = f.x; res[4*i+1] = f.y; res[4*i+2] = f.z; res[4*i+3] = f.w;
  }
#pragma unroll
  for (int k = 0; k < 12; ++k) {
    const int c = half * 12 + k;
    const float* wr = &swoT[c * 24];
    float acc = sbo[c] + res[k];
#pragma unroll
    for (int j = 0; j < 24; ++j) acc += ar[j] * wr[j];
    dout[((size_t)gh * 24 + c) * 88 + gw] = acc;
  }
}

// ============================================================================
extern "C" void kernel_launch(void* const* d_in, const int* in_sizes, int n_in,
                              void* d_out, int out_size, void* d_ws, size_t ws_size,
                              hipStream_t stream)
{
  const float* x      = (const float*)d_in[0];  // [64][352][24]
  const float* qkv_w  = (const float*)d_in[1];  // [4][24][72]
  const float* qkv_b  = (const float*)d_in[2];  // [4][72]
  const float* out_w  = (const float*)d_in[3];  // [4][24][24]
  const float* out_b  = (const float*)d_in[4];  // [4][24]
  float* out = (float*)d_out;                   // [64][24][88]
  float* ws = (float*)d_ws;

  const int N0 = 64 * 352, N1 = 64 * 176, N2 = 64 * 88;
  float* q   = ws;                     // [4][N][6], sized for N0
  float* kvb = q + (size_t)N0 * 24;    // [4][N][12], sized for N0
  float* att = kvb + (size_t)N0 * 48;  // [N][24], sized for N0 (reused L0..L3)
  float* x1  = att + (size_t)N0 * 24;
  float* x2  = x1 + (size_t)N1 * 24;
  float* x3  = x2 + (size_t)N2 * 24;   // total ~10.8 MB

  qkv_first<<<(N0 * 4) / 256, 256, 0, stream>>>(x, qkv_w, qkv_b, q, kvb, N0);

  attn5<<<dim3(44, 8, 4), 128, 0, stream>>>(q, kvb, att, 64, 352);
  glue_pool<<<176, 256, 0, stream>>>(att, x, out_w, out_b,
                                     qkv_w + 1728, qkv_b + 72, x1, q, kvb, N1);

  attn5<<<dim3(22, 8, 4), 128, 0, stream>>>(q, kvb, att, 64, 176);
  glue_pool<<<88, 256, 0, stream>>>(att, x1, out_w + 576, out_b + 24,
                                    qkv_w + 2 * 1728, qkv_b + 2 * 72, x2, q, kvb, N2);

  attn25<<<dim3(11, 16, 4), 256, 0, stream>>>(q, kvb, att);
  glue_nopool<<<88, 256, 0, stream>>>(att, x2, out_w + 2 * 576, out_b + 2 * 24,
                                      qkv_w + 3 * 1728, qkv_b + 3 * 72, x3, q, kvb, N2);

  attn25<<<dim3(11, 16, 4), 256, 0, stream>>>(q, kvb, att);
  final_out<<<44, 256, 0, stream>>>(att, x3, out_w + 3 * 576, out_b + 3 * 24, out);
}